// Round 1
// baseline (936.144 us; speedup 1.0000x reference)
//
#include <hip/hip_runtime.h>

// GraphAttentionLayer: B=4, N=4096, F_IN=F_OUT=128, fp32 in/out.
// Algebra:
//   Wh1[b,i] = q[b,i,:]·c1 + d1,  c1 = Wq_w^T a[:128],  d1 = Wq_b·a[:128]
//   Wh2[b,j] = k[b,j,:]·c2 + d2
//   e_ij = leaky(Wh1_i + Wh2_j); masked softmax over j; h = att @ vp; out = leaky(h @ Wo^T)
// Softmax row-scale invariance + exp(leaky(s)) separability:
//   w_ij = adj_ij * ( Wh2_j >= -Wh1_i ? P1_i*P2_j : Q1_i*Q2_j )
//   P1 = exp(Wh1 - m_i), Q1 = exp(0.1*Wh1 - m_i)  (m_i = leaky(Wh1_i + max_j Wh2) for range)
//   P2 = exp(Wh2),       Q2 = exp(0.1*Wh2)
//   h[i,:] = (sum_j w_ij vp[j,:]) / (sum_j w_ij)

constexpr int B = 4, N = 4096, F = 128;
#define ALPHA 0.1f

__device__ __forceinline__ float leaky(float x) { return x >= 0.f ? x : ALPHA * x; }

// ---------------- K0: c1, c2, d1, d2 ----------------
__global__ void k_prep(const float* __restrict__ Wq_w, const float* __restrict__ Wq_b,
                       const float* __restrict__ Wk_w, const float* __restrict__ Wk_b,
                       const float* __restrict__ a, float* __restrict__ c1,
                       float* __restrict__ c2, float* __restrict__ d12) {
    int f = threadIdx.x;  // 0..127
    float s1 = 0.f, s2 = 0.f;
    for (int o = 0; o < F; o++) {
        s1 = fmaf(Wq_w[o * F + f], a[o], s1);
        s2 = fmaf(Wk_w[o * F + f], a[F + o], s2);
    }
    c1[f] = s1; c2[f] = s2;
    __shared__ float red[F];
    red[f] = Wq_b[f] * a[f];
    __syncthreads();
    for (int s = F / 2; s > 0; s >>= 1) { if (f < s) red[f] += red[f + s]; __syncthreads(); }
    if (f == 0) d12[0] = red[0];
    __syncthreads();
    red[f] = Wk_b[f] * a[F + f];
    __syncthreads();
    for (int s = F / 2; s > 0; s >>= 1) { if (f < s) red[f] += red[f + s]; __syncthreads(); }
    if (f == 0) d12[1] = red[0];
}

// ---------------- K1: Wh1, Wh2 (one 32-lane group per row) ----------------
__global__ void k_wh(const float* __restrict__ q, const float* __restrict__ k,
                     const float* __restrict__ c1, const float* __restrict__ c2,
                     const float* __restrict__ d12,
                     float* __restrict__ Wh1, float* __restrict__ Wh2) {
    __shared__ float c1s[F], c2s[F];
    int t = threadIdx.x;
    if (t < F) c1s[t] = c1[t]; else c2s[t - F] = c2[t - F];
    __syncthreads();
    int row = blockIdx.x * 8 + (t >> 5);
    int lane = t & 31;
    float4 q4 = reinterpret_cast<const float4*>(q)[row * 32 + lane];
    float4 k4 = reinterpret_cast<const float4*>(k)[row * 32 + lane];
    float s1 = q4.x * c1s[lane * 4 + 0] + q4.y * c1s[lane * 4 + 1] +
               q4.z * c1s[lane * 4 + 2] + q4.w * c1s[lane * 4 + 3];
    float s2 = k4.x * c2s[lane * 4 + 0] + k4.y * c2s[lane * 4 + 1] +
               k4.z * c2s[lane * 4 + 2] + k4.w * c2s[lane * 4 + 3];
    for (int m = 16; m > 0; m >>= 1) { s1 += __shfl_xor(s1, m); s2 += __shfl_xor(s2, m); }
    if (lane == 0) { Wh1[row] = s1 + d12[0]; Wh2[row] = s2 + d12[1]; }
}

// ---------------- K1b: per-batch max of Wh2 ----------------
__global__ void k_max2(const float* __restrict__ Wh2, float* __restrict__ M2) {
    int b = blockIdx.x, t = threadIdx.x;
    float m = -1e30f;
    for (int i = t; i < N; i += 256) m = fmaxf(m, Wh2[b * N + i]);
    __shared__ float red[256];
    red[t] = m;
    __syncthreads();
    for (int s = 128; s > 0; s >>= 1) { if (t < s) red[t] = fmaxf(red[t], red[t + s]); __syncthreads(); }
    if (t == 0) M2[b] = red[0];
}

// ---------------- K1c: exp tables ----------------
__global__ void k_tab(const float* __restrict__ Wh1, const float* __restrict__ Wh2,
                      const float* __restrict__ M2,
                      float* __restrict__ P1, float* __restrict__ Q1, float* __restrict__ T1,
                      float* __restrict__ P2, float* __restrict__ Q2) {
    int i = blockIdx.x * 256 + threadIdx.x;  // 0..B*N-1
    int b = i >> 12;                         // N = 4096
    float w1 = Wh1[i], w2 = Wh2[i];
    float mi = leaky(w1 + M2[b]);            // per-row shift (cancels in h; range only)
    P1[i] = __expf(w1 - mi);
    Q1[i] = __expf(ALPHA * w1 - mi);
    T1[i] = -w1;
    P2[i] = __expf(w2);
    Q2[i] = __expf(ALPHA * w2);
}

// ---------------- K2: vp = v @ Wv^T + bv ----------------
__global__ void k_vp(const float* __restrict__ v, const float* __restrict__ Wv_w,
                     const float* __restrict__ Wv_b, float* __restrict__ vp) {
    __shared__ float vs[32][F];  // 16 KB
    int t = threadIdx.x;
    int row0 = blockIdx.x * 32;
    {
        const float4* src = reinterpret_cast<const float4*>(v + row0 * F);
        float4* dst = reinterpret_cast<float4*>(&vs[0][0]);
#pragma unroll
        for (int u = 0; u < 4; u++) dst[t + u * 256] = src[t + u * 256];
    }
    __syncthreads();
    int f = t & 127;
    int g = t >> 7;  // row group: rows g*16 .. g*16+15
    float acc[16];
    float bias = Wv_b[f];
#pragma unroll
    for (int r = 0; r < 16; r++) acc[r] = bias;
    const float* wrow = Wv_w + f * F;
    for (int kk = 0; kk < F; kk++) {
        float wk = wrow[kk];
#pragma unroll
        for (int r = 0; r < 16; r++) acc[r] = fmaf(vs[g * 16 + r][kk], wk, acc[r]);
    }
#pragma unroll
    for (int r = 0; r < 16; r++) vp[(row0 + g * 16 + r) * F + f] = acc[r];
}

// ---------------- K3: masked-softmax attention x vp (the big one) ----------------
__global__ void k_attn(const float* __restrict__ vp, const int* __restrict__ adj,
                       const float* __restrict__ P1, const float* __restrict__ Q1,
                       const float* __restrict__ T1, const float* __restrict__ P2,
                       const float* __restrict__ Q2, const float* __restrict__ Wh2,
                       float* __restrict__ h) {
    __shared__ float vps[32][F];   // 16 KB
    __shared__ float wsm[64][33];  // 8.25 KB, padded to kill bank conflicts
    __shared__ float P1s[64], Q1s[64], T1s[64];
    __shared__ float P2s[32], Q2s[32], W2s[32];
    int t = threadIdx.x;
    int tile = blockIdx.x & 63;  // 64 row-tiles per batch
    int b = blockIdx.x >> 6;
    int i0 = tile * 64;
    if (t < 64) {
        int gi = b * N + i0 + t;
        P1s[t] = P1[gi]; Q1s[t] = Q1[gi]; T1s[t] = T1[gi];
    }
    int ty = t >> 4, tx = t & 15;  // thread owns rows ty*4..+3, cols tx*8..+7
    float acc[4][8];
#pragma unroll
    for (int r = 0; r < 4; r++)
#pragma unroll
        for (int c = 0; c < 8; c++) acc[r][c] = 0.f;
    float den[4] = {0.f, 0.f, 0.f, 0.f};
    const int* adjb = adj + (long long)b * N * N;

    for (int j0 = 0; j0 < N; j0 += 32) {
        {  // stage vp tile
            const float4* src = reinterpret_cast<const float4*>(vp + (b * N + j0) * F);
            float4* dst = reinterpret_cast<float4*>(&vps[0][0]);
#pragma unroll
            for (int u = 0; u < 4; u++) dst[t + u * 256] = src[t + u * 256];
        }
        if (t < 32) {
            int gj = b * N + j0 + t;
            P2s[t] = P2[gj]; Q2s[t] = Q2[gj]; W2s[t] = Wh2[gj];
        }
        __syncthreads();
        {  // compute 64x32 w tile: thread covers i_loc = t>>2, j = (t&3)*8..+7
            int il = t >> 2;
            int jb = (t & 3) * 8;
            const int* arow = adjb + (i0 + il) * N + j0 + jb;
            int4 a0 = *reinterpret_cast<const int4*>(arow);
            int4 a1 = *reinterpret_cast<const int4*>(arow + 4);
            float p1 = P1s[il], q1 = Q1s[il], t1 = T1s[il];
            int av[8] = {a0.x, a0.y, a0.z, a0.w, a1.x, a1.y, a1.z, a1.w};
#pragma unroll
            for (int u = 0; u < 8; u++) {
                int j = jb + u;
                float w = (W2s[j] >= t1) ? p1 * P2s[j] : q1 * Q2s[j];
                wsm[il][j] = av[u] ? w : 0.f;
            }
        }
        __syncthreads();
#pragma unroll 4
        for (int jj = 0; jj < 32; jj++) {
            float wr[4];
#pragma unroll
            for (int r = 0; r < 4; r++) wr[r] = wsm[ty * 4 + r][jj];
            float4 v0 = *reinterpret_cast<const float4*>(&vps[jj][tx * 8]);
            float4 v1 = *reinterpret_cast<const float4*>(&vps[jj][tx * 8 + 4]);
            float vv[8] = {v0.x, v0.y, v0.z, v0.w, v1.x, v1.y, v1.z, v1.w};
#pragma unroll
            for (int r = 0; r < 4; r++) {
                den[r] += wr[r];
#pragma unroll
                for (int c = 0; c < 8; c++) acc[r][c] = fmaf(wr[r], vv[c], acc[r][c]);
            }
        }
        __syncthreads();
    }
#pragma unroll
    for (int r = 0; r < 4; r++) {
        float inv = 1.f / den[r];
        int row = b * N + i0 + ty * 4 + r;
        float4 o0 = make_float4(acc[r][0] * inv, acc[r][1] * inv, acc[r][2] * inv, acc[r][3] * inv);
        float4 o1 = make_float4(acc[r][4] * inv, acc[r][5] * inv, acc[r][6] * inv, acc[r][7] * inv);
        *reinterpret_cast<float4*>(&h[row * F + tx * 8]) = o0;
        *reinterpret_cast<float4*>(&h[row * F + tx * 8 + 4]) = o1;
    }
}

// ---------------- K4: out = leaky(h @ Wo^T) ----------------
__global__ void k_out(const float* __restrict__ h, const float* __restrict__ Wo_w,
                      float* __restrict__ out) {
    __shared__ float hs[32][F];
    int t = threadIdx.x;
    int row0 = blockIdx.x * 32;
    {
        const float4* src = reinterpret_cast<const float4*>(h + row0 * F);
        float4* dst = reinterpret_cast<float4*>(&hs[0][0]);
#pragma unroll
        for (int u = 0; u < 4; u++) dst[t + u * 256] = src[t + u * 256];
    }
    __syncthreads();
    int f = t & 127, g = t >> 7;
    float acc[16];
#pragma unroll
    for (int r = 0; r < 16; r++) acc[r] = 0.f;
    const float* wrow = Wo_w + f * F;
    for (int kk = 0; kk < F; kk++) {
        float wk = wrow[kk];
#pragma unroll
        for (int r = 0; r < 16; r++) acc[r] = fmaf(hs[g * 16 + r][kk], wk, acc[r]);
    }
#pragma unroll
    for (int r = 0; r < 16; r++) out[(row0 + g * 16 + r) * F + f] = leaky(acc[r]);
}

extern "C" void kernel_launch(void* const* d_in, const int* in_sizes, int n_in,
                              void* d_out, int out_size, void* d_ws, size_t ws_size,
                              hipStream_t stream) {
    const float* q    = (const float*)d_in[0];
    const float* k    = (const float*)d_in[1];
    const float* v    = (const float*)d_in[2];
    const int*   adj  = (const int*)d_in[3];
    const float* Wq_w = (const float*)d_in[4];
    const float* Wq_b = (const float*)d_in[5];
    const float* Wk_w = (const float*)d_in[6];
    const float* Wk_b = (const float*)d_in[7];
    const float* Wv_w = (const float*)d_in[8];
    const float* Wv_b = (const float*)d_in[9];
    const float* a    = (const float*)d_in[10];
    const float* Wo_w = (const float*)d_in[11];
    float* out = (float*)d_out;
    float* ws = (float*)d_ws;

    const int BN = B * N;
    float* vp  = ws;             // BN*F
    float* h   = vp + BN * F;    // BN*F
    float* Wh1 = h + BN * F;     // BN
    float* Wh2 = Wh1 + BN;       // BN
    float* P1  = Wh2 + BN;       // BN
    float* Q1  = P1 + BN;        // BN
    float* T1  = Q1 + BN;        // BN
    float* P2  = T1 + BN;        // BN
    float* Q2  = P2 + BN;        // BN
    float* c1  = Q2 + BN;        // F
    float* c2  = c1 + F;         // F
    float* d12 = c2 + F;         // 2
    float* M2  = d12 + 2;        // B

    k_prep<<<1, F, 0, stream>>>(Wq_w, Wq_b, Wk_w, Wk_b, a, c1, c2, d12);
    k_wh<<<BN / 8, 256, 0, stream>>>(q, k, c1, c2, d12, Wh1, Wh2);
    k_max2<<<B, 256, 0, stream>>>(Wh2, M2);
    k_tab<<<BN / 256, 256, 0, stream>>>(Wh1, Wh2, M2, P1, Q1, T1, P2, Q2);
    k_vp<<<BN / 32, 256, 0, stream>>>(v, Wv_w, Wv_b, vp);
    k_attn<<<B * (N / 64), 256, 0, stream>>>(vp, adj, P1, Q1, T1, P2, Q2, Wh2, h);
    k_out<<<BN / 32, 256, 0, stream>>>(h, Wo_w, out);
}

// Round 2
// 511.323 us; speedup vs baseline: 1.8308x; 1.8308x over previous
//
#include <hip/hip_runtime.h>

// GraphAttentionLayer: B=4, N=4096, F=128, fp32 in/out.
//   w_ij = adj_ij * ( Wh2_j >= -Wh1_i ? P1_i*P2_j : Q1_i*Q2_j )   (softmax scale-invariance
//   + separability of exp(leaky(x+y)) per branch), h = (w @ vp) / rowsum(w), out = leaky(h@Wo^T).
// k_attn: bf16 MFMA 16x16x32; A-frag (w) generated in-register, B-frag (vpT) via padded LDS.
// j-split x2 with fp32 atomicAdd partial numerator/denominator; k_out fuses combine+divide+GEMM.

constexpr int B = 4, N = 4096, F = 128;
constexpr int BN = B * N;
constexpr int BK = 64;
#define ALPHA 0.1f

using float4v = __attribute__((ext_vector_type(4))) float;
using short8 = __attribute__((ext_vector_type(8))) short;

__device__ __forceinline__ float leaky(float x) { return x >= 0.f ? x : ALPHA * x; }
__device__ __forceinline__ unsigned short f2bf(float x) {  // RNE float->bf16
    unsigned u = __float_as_uint(x);
    u = (u + 0x7FFFu + ((u >> 16) & 1u)) >> 16;
    return (unsigned short)u;
}

// ---------------- K0: c1, c2, d1, d2 ----------------
__global__ void k_prep(const float* __restrict__ Wq_w, const float* __restrict__ Wq_b,
                       const float* __restrict__ Wk_w, const float* __restrict__ Wk_b,
                       const float* __restrict__ a, float* __restrict__ c1,
                       float* __restrict__ c2, float* __restrict__ d12) {
    __shared__ float as[2 * F];
    __shared__ float red[2 * F];
    int t = threadIdx.x;  // 256
    as[t] = a[t];
    __syncthreads();
    int f = t & 127;
    const float* W = (t < F) ? Wq_w : Wk_w;
    const float* ao = (t < F) ? as : as + F;
    float s = 0.f;
#pragma unroll 8
    for (int o = 0; o < F; o++) s = fmaf(W[o * F + f], ao[o], s);
    if (t < F) c1[f] = s; else c2[f] = s;
    red[t] = (t < F) ? Wq_b[f] * as[f] : Wk_b[f] * as[F + f];
    __syncthreads();
    for (int st = 64; st > 0; st >>= 1) {
        if (f < st) red[t] += red[t + st];
        __syncthreads();
    }
    if (t == 0) d12[0] = red[0];
    if (t == F) d12[1] = red[F];
}

// ---------------- K1: Wh1, Wh2 ----------------
__global__ void k_wh(const float* __restrict__ q, const float* __restrict__ k,
                     const float* __restrict__ c1, const float* __restrict__ c2,
                     const float* __restrict__ d12,
                     float* __restrict__ Wh1, float* __restrict__ Wh2) {
    __shared__ float c1s[F], c2s[F];
    int t = threadIdx.x;
    if (t < F) c1s[t] = c1[t]; else c2s[t - F] = c2[t - F];
    __syncthreads();
    int row = blockIdx.x * 8 + (t >> 5);
    int lane = t & 31;
    float4 q4 = reinterpret_cast<const float4*>(q)[row * 32 + lane];
    float4 k4 = reinterpret_cast<const float4*>(k)[row * 32 + lane];
    float s1 = q4.x * c1s[lane * 4 + 0] + q4.y * c1s[lane * 4 + 1] +
               q4.z * c1s[lane * 4 + 2] + q4.w * c1s[lane * 4 + 3];
    float s2 = k4.x * c2s[lane * 4 + 0] + k4.y * c2s[lane * 4 + 1] +
               k4.z * c2s[lane * 4 + 2] + k4.w * c2s[lane * 4 + 3];
    for (int m = 16; m > 0; m >>= 1) { s1 += __shfl_xor(s1, m); s2 += __shfl_xor(s2, m); }
    if (lane == 0) { Wh1[row] = s1 + d12[0]; Wh2[row] = s2 + d12[1]; }
}

// ---------------- K1b: per-batch max of Wh2 ----------------
__global__ void k_max2(const float* __restrict__ Wh2, float* __restrict__ M2) {
    int b = blockIdx.x, t = threadIdx.x;
    float m = -1e30f;
    for (int i = t; i < N; i += 256) m = fmaxf(m, Wh2[b * N + i]);
    __shared__ float red[256];
    red[t] = m;
    __syncthreads();
    for (int s = 128; s > 0; s >>= 1) { if (t < s) red[t] = fmaxf(red[t], red[t + s]); __syncthreads(); }
    if (t == 0) M2[b] = red[0];
}

// ---------------- K1c: exp tables ----------------
__global__ void k_tab(const float* __restrict__ Wh1, const float* __restrict__ Wh2,
                      const float* __restrict__ M2,
                      float* __restrict__ P1, float* __restrict__ Q1,
                      float* __restrict__ P2, float* __restrict__ Q2) {
    int i = blockIdx.x * 256 + threadIdx.x;
    int b = i >> 12;  // N = 4096
    float w1 = Wh1[i], w2 = Wh2[i];
    float mi = leaky(w1 + M2[b]);  // per-row shift (cancels in h; range only)
    P1[i] = __expf(w1 - mi);
    Q1[i] = __expf(ALPHA * w1 - mi);
    P2[i] = __expf(w2);
    Q2[i] = __expf(ALPHA * w2);
}

// ---------------- K2: vpT = bf16( (v @ Wv^T + bv)^T ), layout [B][F][N] ----------------
__global__ __launch_bounds__(256) void k_vp(const float* __restrict__ v,
                                            const float* __restrict__ Wv_w,
                                            const float* __restrict__ Wv_b,
                                            unsigned short* __restrict__ vpT) {
    __shared__ float vs[32][F];            // 16 KB
    __shared__ float Ws[F][129];           // 66 KB, pad -> 2-way bank (free)
    __shared__ unsigned short ts[F][40];   // 10 KB transpose tile (pad 8)
    int t = threadIdx.x;
    int row0g = blockIdx.x * 32;           // flat row in [0, BN)
    int b = row0g >> 12;
    int row0 = row0g & (N - 1);
    {
        const float4* src = reinterpret_cast<const float4*>(v + row0g * F);
        float4* dst = reinterpret_cast<float4*>(&vs[0][0]);
#pragma unroll
        for (int u = 0; u < 4; u++) dst[u * 256 + t] = src[u * 256 + t];
    }
    {
        const float4* src = reinterpret_cast<const float4*>(Wv_w);
#pragma unroll
        for (int u = 0; u < 16; u++) {
            int unit = u * 256 + t;
            int r = unit >> 5, s = unit & 31;
            float4 val = src[unit];
            Ws[r][s * 4 + 0] = val.x; Ws[r][s * 4 + 1] = val.y;
            Ws[r][s * 4 + 2] = val.z; Ws[r][s * 4 + 3] = val.w;
        }
    }
    int f = t & 127, g = t >> 7;
    float bias = Wv_b[f];
    __syncthreads();
    float acc[16];
#pragma unroll
    for (int r = 0; r < 16; r++) acc[r] = bias;
    for (int kk = 0; kk < F; kk++) {
        float wk = Ws[f][kk];
#pragma unroll
        for (int r = 0; r < 16; r++) acc[r] = fmaf(vs[g * 16 + r][kk], wk, acc[r]);
    }
#pragma unroll
    for (int r = 0; r < 16; r++) ts[f][g * 16 + r] = f2bf(acc[r]);
    __syncthreads();
    int fr = t >> 1, hseg = t & 1;
    uint4 d0 = *reinterpret_cast<uint4*>(&ts[fr][hseg * 16]);
    uint4 d1 = *reinterpret_cast<uint4*>(&ts[fr][hseg * 16 + 8]);
    unsigned short* dst = vpT + ((size_t)(b * F + fr) * N + row0 + hseg * 16);
    *reinterpret_cast<uint4*>(dst) = d0;
    *reinterpret_cast<uint4*>(dst + 8) = d1;
}

// ---------------- K3: MFMA attention, j-split x2, atomic partials ----------------
__global__ __launch_bounds__(256) void k_attn(
    const unsigned short* __restrict__ vpT, const int* __restrict__ adj,
    const float* __restrict__ Wh1, const float* __restrict__ P1, const float* __restrict__ Q1,
    const float* __restrict__ P2, const float* __restrict__ Q2, const float* __restrict__ Wh2,
    float* __restrict__ h_part, float* __restrict__ den_part) {
    __shared__ unsigned short bs[F][72];   // vpT tile [f][k], pad 72 -> 2-way frag reads
    __shared__ float P2s[BK], Q2s[BK], W2s[BK];
    int t = threadIdx.x;
    int idx = blockIdx.x;          // 512 = B * 64 tiles * 2 halves
    int half = idx & 1;
    int tile = (idx >> 1) & 63;
    int b = idx >> 7;
    int i0 = tile * 64;
    int jb0 = half * 2048;
    int widx = t >> 6, lane = t & 63, m = lane & 15, q = lane >> 4;
    int row = i0 + widx * 16 + m;  // this lane's A-row
    int gi = b * N + row;
    float p1 = P1[gi], q1 = Q1[gi], t1 = -Wh1[gi];
    const int* adjr = adj + (long long)gi * N + jb0;
    const unsigned short* vb = vpT + (size_t)b * F * N + jb0;
    const float* P2g = P2 + b * N + jb0;
    const float* Q2g = Q2 + b * N + jb0;
    const float* W2g = Wh2 + b * N + jb0;

    float4v acc[8];
#pragma unroll
    for (int nt = 0; nt < 8; nt++) acc[nt] = (float4v){0.f, 0.f, 0.f, 0.f};
    float den = 0.f;

    for (int j0 = 0; j0 < 2048; j0 += BK) {
        {  // stage B tile: 128 rows x 64 k bf16 (128 B/row), 1024 16B units
#pragma unroll
            for (int u = 0; u < 4; u++) {
                int unit = u * 256 + t;
                int r = unit >> 3, s = unit & 7;
                *reinterpret_cast<uint4*>(&bs[r][s * 8]) =
                    *reinterpret_cast<const uint4*>(vb + (size_t)r * N + j0 + s * 8);
            }
        }
        if (t < 64) P2s[t] = P2g[j0 + t];
        else if (t < 128) Q2s[t - 64] = Q2g[j0 + t - 64];
        else if (t < 192) W2s[t - 128] = W2g[j0 + t - 128];
        __syncthreads();
#pragma unroll
        for (int kh = 0; kh < 2; kh++) {
            int jl = kh * 32 + q * 8;
            int4 a0 = *reinterpret_cast<const int4*>(adjr + j0 + jl);
            int4 a1 = *reinterpret_cast<const int4*>(adjr + j0 + jl + 4);
            float4 p2a = *reinterpret_cast<const float4*>(&P2s[jl]);
            float4 p2b = *reinterpret_cast<const float4*>(&P2s[jl + 4]);
            float4 q2a = *reinterpret_cast<const float4*>(&Q2s[jl]);
            float4 q2b = *reinterpret_cast<const float4*>(&Q2s[jl + 4]);
            float4 x2a = *reinterpret_cast<const float4*>(&W2s[jl]);
            float4 x2b = *reinterpret_cast<const float4*>(&W2s[jl + 4]);
            float w0 = a0.x ? ((x2a.x >= t1) ? p1 * p2a.x : q1 * q2a.x) : 0.f;
            float w1 = a0.y ? ((x2a.y >= t1) ? p1 * p2a.y : q1 * q2a.y) : 0.f;
            float w2 = a0.z ? ((x2a.z >= t1) ? p1 * p2a.z : q1 * q2a.z) : 0.f;
            float w3 = a0.w ? ((x2a.w >= t1) ? p1 * p2a.w : q1 * q2a.w) : 0.f;
            float w4 = a1.x ? ((x2b.x >= t1) ? p1 * p2b.x : q1 * q2b.x) : 0.f;
            float w5 = a1.y ? ((x2b.y >= t1) ? p1 * p2b.y : q1 * q2b.y) : 0.f;
            float w6 = a1.z ? ((x2b.z >= t1) ? p1 * p2b.z : q1 * q2b.z) : 0.f;
            float w7 = a1.w ? ((x2b.w >= t1) ? p1 * p2b.w : q1 * q2b.w) : 0.f;
            den += ((w0 + w1) + (w2 + w3)) + ((w4 + w5) + (w6 + w7));
            short8 af;
            af[0] = (short)f2bf(w0); af[1] = (short)f2bf(w1);
            af[2] = (short)f2bf(w2); af[3] = (short)f2bf(w3);
            af[4] = (short)f2bf(w4); af[5] = (short)f2bf(w5);
            af[6] = (short)f2bf(w6); af[7] = (short)f2bf(w7);
#pragma unroll
            for (int nt = 0; nt < 8; nt++) {
                short8 bf = *reinterpret_cast<const short8*>(&bs[nt * 16 + m][kh * 32 + q * 8]);
                acc[nt] = __builtin_amdgcn_mfma_f32_16x16x32_bf16(af, bf, acc[nt], 0, 0, 0);
            }
        }
        __syncthreads();
    }
    den += __shfl_xor(den, 16);
    den += __shfl_xor(den, 32);
    if (q == 0) atomicAdd(&den_part[gi], den);
    int orow = b * N + i0 + widx * 16 + q * 4;  // C/D: row = q*4+reg, col = m
#pragma unroll
    for (int nt = 0; nt < 8; nt++)
#pragma unroll
        for (int r = 0; r < 4; r++)
            atomicAdd(&h_part[(size_t)(orow + r) * F + nt * 16 + m], acc[nt][r]);
}

// ---------------- K4: out = leaky( ((h_num/den) @ Wo^T) ) ----------------
__global__ __launch_bounds__(256) void k_out(const float* __restrict__ h_part,
                                             const float* __restrict__ den_part,
                                             const float* __restrict__ Wo_w,
                                             float* __restrict__ out) {
    __shared__ float hs[32][F];    // 16 KB
    __shared__ float Ws[F][129];   // 66 KB
    int t = threadIdx.x;
    int row0 = blockIdx.x * 32;    // flat row in [0, BN)
    {
        const float4* src = reinterpret_cast<const float4*>(Wo_w);
#pragma unroll
        for (int u = 0; u < 16; u++) {
            int unit = u * 256 + t;
            int r = unit >> 5, s = unit & 31;
            float4 val = src[unit];
            Ws[r][s * 4 + 0] = val.x; Ws[r][s * 4 + 1] = val.y;
            Ws[r][s * 4 + 2] = val.z; Ws[r][s * 4 + 3] = val.w;
        }
    }
#pragma unroll
    for (int u = 0; u < 4; u++) {
        int unit = u * 256 + t;
        int r = unit >> 5, s = unit & 31;
        float4 hv = *reinterpret_cast<const float4*>(h_part + (size_t)(row0 + r) * F + s * 4);
        float inv = 1.f / den_part[row0 + r];
        float4 o = make_float4(hv.x * inv, hv.y * inv, hv.z * inv, hv.w * inv);
        *reinterpret_cast<float4*>(&hs[r][s * 4]) = o;
    }
    __syncthreads();
    int f = t & 127, g = t >> 7;
    float acc[16];
#pragma unroll
    for (int r = 0; r < 16; r++) acc[r] = 0.f;
    for (int kk = 0; kk < F; kk++) {
        float wk = Ws[f][kk];
#pragma unroll
        for (int r = 0; r < 16; r++) acc[r] = fmaf(hs[g * 16 + r][kk], wk, acc[r]);
    }
#pragma unroll
    for (int r = 0; r < 16; r++) out[(size_t)(row0 + g * 16 + r) * F + f] = leaky(acc[r]);
}

extern "C" void kernel_launch(void* const* d_in, const int* in_sizes, int n_in,
                              void* d_out, int out_size, void* d_ws, size_t ws_size,
                              hipStream_t stream) {
    const float* q    = (const float*)d_in[0];
    const float* k    = (const float*)d_in[1];
    const float* v    = (const float*)d_in[2];
    const int*   adj  = (const int*)d_in[3];
    const float* Wq_w = (const float*)d_in[4];
    const float* Wq_b = (const float*)d_in[5];
    const float* Wk_w = (const float*)d_in[6];
    const float* Wk_b = (const float*)d_in[7];
    const float* Wv_w = (const float*)d_in[8];
    const float* Wv_b = (const float*)d_in[9];
    const float* a    = (const float*)d_in[10];
    const float* Wo_w = (const float*)d_in[11];
    float* out = (float*)d_out;
    float* ws = (float*)d_ws;

    unsigned short* vpT = (unsigned short*)ws;        // BN*F bf16 = BN*F/2 floats
    float* h_part   = ws + BN * F / 2;                // BN*F
    float* den_part = h_part + BN * F;                // BN
    float* Wh1 = den_part + BN;                       // BN
    float* Wh2 = Wh1 + BN;
    float* P1  = Wh2 + BN;
    float* Q1  = P1 + BN;
    float* P2  = Q1 + BN;
    float* Q2  = P2 + BN;
    float* c1  = Q2 + BN;                             // F
    float* c2  = c1 + F;                              // F
    float* d12 = c2 + F;                              // 2
    float* M2  = d12 + 2;                             // B

    hipMemsetAsync(h_part, 0, (size_t)(BN * F + BN) * sizeof(float), stream);
    k_prep<<<1, 256, 0, stream>>>(Wq_w, Wq_b, Wk_w, Wk_b, a, c1, c2, d12);
    k_wh<<<BN / 8, 256, 0, stream>>>(q, k, c1, c2, d12, Wh1, Wh2);
    k_max2<<<B, 256, 0, stream>>>(Wh2, M2);
    k_tab<<<BN / 256, 256, 0, stream>>>(Wh1, Wh2, M2, P1, Q1, P2, Q2);
    k_vp<<<BN / 32, 256, 0, stream>>>(v, Wv_w, Wv_b, vpT);
    k_attn<<<B * 64 * 2, 256, 0, stream>>>(vpT, adj, Wh1, P1, Q1, P2, Q2, Wh2, h_part, den_part);
    k_out<<<BN / 32, 256, 0, stream>>>(h_part, den_part, Wo_w, out);
}

// Round 3
// 508.349 us; speedup vs baseline: 1.8415x; 1.0059x over previous
//
#include <hip/hip_runtime.h>

// GraphAttentionLayer: B=4, N=4096, F=128, fp32 in/out.
//   w_ij = adj_ij * ( Wh2_j >= -Wh1_i ? P1_i*P2_j : Q1_i*Q2_j )   (softmax scale-invariance
//   + separability of exp(leaky(x+y)) per branch), h = (w @ vp) / rowsum(w), out = leaky(h@Wo^T).
// k_attn v3: software-pipelined (adj + staging register prefetch, LDS double-buffer),
// M=128/block (2 row-tiles per wave sharing B-frags), 4-way j-split with non-atomic
// per-split partial buffers. k_out combines 4 partials + divide + GEMM + leaky.

constexpr int B = 4, N = 4096, F = 128;
constexpr int BN = B * N;
constexpr int BK = 64;
constexpr int SPLITS = 4;
constexpr int JC = N / SPLITS;   // 1024 j per block
constexpr int NIT = JC / BK;     // 16 iterations
#define ALPHA 0.1f

using float4v = __attribute__((ext_vector_type(4))) float;
using short8 = __attribute__((ext_vector_type(8))) short;

__device__ __forceinline__ float leaky(float x) { return x >= 0.f ? x : ALPHA * x; }
__device__ __forceinline__ unsigned short f2bf(float x) {  // RNE float->bf16
    unsigned u = __float_as_uint(x);
    u = (u + 0x7FFFu + ((u >> 16) & 1u)) >> 16;
    return (unsigned short)u;
}
// pack two floats -> two RNE bf16 in one dword: {bf(hi)[31:16], bf(lo)[15:0]}
__device__ __forceinline__ unsigned pack_bf2(float lo, float hi) {
    unsigned a = __float_as_uint(lo), b2 = __float_as_uint(hi);
    a = a + 0x7FFFu + ((a >> 16) & 1u);
    b2 = b2 + 0x7FFFu + ((b2 >> 16) & 1u);
    return __builtin_amdgcn_perm(b2, a, 0x07060302u);  // bytes: b2[3],b2[2],a[3],a[2]
}

// ---------------- K0: c1, c2, d1, d2 ----------------
__global__ void k_prep(const float* __restrict__ Wq_w, const float* __restrict__ Wq_b,
                       const float* __restrict__ Wk_w, const float* __restrict__ Wk_b,
                       const float* __restrict__ a, float* __restrict__ c1,
                       float* __restrict__ c2, float* __restrict__ d12) {
    __shared__ float as[2 * F];
    __shared__ float red[2 * F];
    int t = threadIdx.x;  // 256
    as[t] = a[t];
    __syncthreads();
    int f = t & 127;
    const float* W = (t < F) ? Wq_w : Wk_w;
    const float* ao = (t < F) ? as : as + F;
    float s = 0.f;
#pragma unroll 8
    for (int o = 0; o < F; o++) s = fmaf(W[o * F + f], ao[o], s);
    if (t < F) c1[f] = s; else c2[f] = s;
    red[t] = (t < F) ? Wq_b[f] * as[f] : Wk_b[f] * as[F + f];
    __syncthreads();
    for (int st = 64; st > 0; st >>= 1) {
        if (f < st) red[t] += red[t + st];
        __syncthreads();
    }
    if (t == 0) d12[0] = red[0];
    if (t == F) d12[1] = red[F];
}

// ---------------- K1: Wh1, Wh2 ----------------
__global__ void k_wh(const float* __restrict__ q, const float* __restrict__ k,
                     const float* __restrict__ c1, const float* __restrict__ c2,
                     const float* __restrict__ d12,
                     float* __restrict__ Wh1, float* __restrict__ Wh2) {
    __shared__ float c1s[F], c2s[F];
    int t = threadIdx.x;
    if (t < F) c1s[t] = c1[t]; else c2s[t - F] = c2[t - F];
    __syncthreads();
    int row = blockIdx.x * 8 + (t >> 5);
    int lane = t & 31;
    float4 q4 = reinterpret_cast<const float4*>(q)[row * 32 + lane];
    float4 k4 = reinterpret_cast<const float4*>(k)[row * 32 + lane];
    float s1 = q4.x * c1s[lane * 4 + 0] + q4.y * c1s[lane * 4 + 1] +
               q4.z * c1s[lane * 4 + 2] + q4.w * c1s[lane * 4 + 3];
    float s2 = k4.x * c2s[lane * 4 + 0] + k4.y * c2s[lane * 4 + 1] +
               k4.z * c2s[lane * 4 + 2] + k4.w * c2s[lane * 4 + 3];
    for (int m = 16; m > 0; m >>= 1) { s1 += __shfl_xor(s1, m); s2 += __shfl_xor(s2, m); }
    if (lane == 0) { Wh1[row] = s1 + d12[0]; Wh2[row] = s2 + d12[1]; }
}

// ---------------- K1b: per-batch max of Wh2 ----------------
__global__ void k_max2(const float* __restrict__ Wh2, float* __restrict__ M2) {
    int b = blockIdx.x, t = threadIdx.x;
    float m = -1e30f;
    for (int i = t; i < N; i += 256) m = fmaxf(m, Wh2[b * N + i]);
    __shared__ float red[256];
    red[t] = m;
    __syncthreads();
    for (int s = 128; s > 0; s >>= 1) { if (t < s) red[t] = fmaxf(red[t], red[t + s]); __syncthreads(); }
    if (t == 0) M2[b] = red[0];
}

// ---------------- K1c: exp tables ----------------
__global__ void k_tab(const float* __restrict__ Wh1, const float* __restrict__ Wh2,
                      const float* __restrict__ M2,
                      float* __restrict__ P1, float* __restrict__ Q1,
                      float* __restrict__ P2, float* __restrict__ Q2) {
    int i = blockIdx.x * 256 + threadIdx.x;
    int b = i >> 12;  // N = 4096
    float w1 = Wh1[i], w2 = Wh2[i];
    float mi = leaky(w1 + M2[b]);  // per-row shift (cancels in h; range only)
    P1[i] = __expf(w1 - mi);
    Q1[i] = __expf(ALPHA * w1 - mi);
    P2[i] = __expf(w2);
    Q2[i] = __expf(ALPHA * w2);
}

// ---------------- K2: vpT = bf16( (v @ Wv^T + bv)^T ), layout [B][F][N] ----------------
__global__ __launch_bounds__(256) void k_vp(const float* __restrict__ v,
                                            const float* __restrict__ Wv_w,
                                            const float* __restrict__ Wv_b,
                                            unsigned short* __restrict__ vpT) {
    __shared__ float vs[32][F];            // 16 KB
    __shared__ float Ws[F][129];           // 66 KB, pad -> conflict-free column reads
    __shared__ unsigned short ts[F][40];   // 10 KB transpose tile (pad 8)
    int t = threadIdx.x;
    int row0g = blockIdx.x * 32;           // flat row in [0, BN)
    int b = row0g >> 12;
    int row0 = row0g & (N - 1);
    {
        const float4* src = reinterpret_cast<const float4*>(v + row0g * F);
        float4* dst = reinterpret_cast<float4*>(&vs[0][0]);
#pragma unroll
        for (int u = 0; u < 4; u++) dst[u * 256 + t] = src[u * 256 + t];
    }
    {
        const float4* src = reinterpret_cast<const float4*>(Wv_w);
#pragma unroll
        for (int u = 0; u < 16; u++) {
            int unit = u * 256 + t;
            int r = unit >> 5, s = unit & 31;
            float4 val = src[unit];
            Ws[r][s * 4 + 0] = val.x; Ws[r][s * 4 + 1] = val.y;
            Ws[r][s * 4 + 2] = val.z; Ws[r][s * 4 + 3] = val.w;
        }
    }
    int f = t & 127, g = t >> 7;
    float bias = Wv_b[f];
    __syncthreads();
    float acc[16];
#pragma unroll
    for (int r = 0; r < 16; r++) acc[r] = bias;
    for (int kk = 0; kk < F; kk++) {
        float wk = Ws[f][kk];
#pragma unroll
        for (int r = 0; r < 16; r++) acc[r] = fmaf(vs[g * 16 + r][kk], wk, acc[r]);
    }
#pragma unroll
    for (int r = 0; r < 16; r++) ts[f][g * 16 + r] = f2bf(acc[r]);
    __syncthreads();
    int fr = t >> 1, hseg = t & 1;
    uint4 d0 = *reinterpret_cast<uint4*>(&ts[fr][hseg * 16]);
    uint4 d1 = *reinterpret_cast<uint4*>(&ts[fr][hseg * 16 + 8]);
    unsigned short* dst = vpT + ((size_t)(b * F + fr) * N + row0 + hseg * 16);
    *reinterpret_cast<uint4*>(dst) = d0;
    *reinterpret_cast<uint4*>(dst + 8) = d1;
}

// ---------------- K3: MFMA attention, pipelined, 4-way j-split, plain stores ----------------
__global__ __launch_bounds__(256, 2) void k_attn(
    const unsigned short* __restrict__ vpT, const int* __restrict__ adj,
    const float* __restrict__ Wh1, const float* __restrict__ P1, const float* __restrict__ Q1,
    const float* __restrict__ P2, const float* __restrict__ Q2, const float* __restrict__ Wh2,
    float* __restrict__ h_part, float* __restrict__ den_part) {
    __shared__ __align__(16) unsigned short bs[2][F][72];  // 36.9 KB dbuf, pad 72
    __shared__ __align__(16) float sP2[JC], sQ2[JC], sW2[JC];  // 12 KB
    int t = threadIdx.x;
    int idx = blockIdx.x;            // 512 = B * 32 tiles * 4 splits
    int split = idx & 3;
    int tile = (idx >> 2) & 31;
    int b = idx >> 7;
    int i0 = tile * 128;
    int jb0 = split * JC;
    int widx = t >> 6, lane = t & 63, m = lane & 15, q = lane >> 4;
    int r0 = i0 + widx * 32;         // wave's first row (covers 32 rows: 2 tiles of 16)

    {  // preload P2/Q2/W2 for the whole j-slice (1024 floats each)
        reinterpret_cast<float4*>(sP2)[t] = reinterpret_cast<const float4*>(P2 + b * N + jb0)[t];
        reinterpret_cast<float4*>(sQ2)[t] = reinterpret_cast<const float4*>(Q2 + b * N + jb0)[t];
        reinterpret_cast<float4*>(sW2)[t] = reinterpret_cast<const float4*>(Wh2 + b * N + jb0)[t];
    }

    int gi0 = b * N + r0 + m;        // rt=0 row of this lane
    int gi1 = gi0 + 16;              // rt=1 row
    float p1a = P1[gi0], q1a = Q1[gi0], t1a = -Wh1[gi0];
    float p1b = P1[gi1], q1b = Q1[gi1], t1b = -Wh1[gi1];

    const unsigned short* vb = vpT + (size_t)b * F * N + jb0;
    const int* adjbase = adj + (size_t)gi0 * N + jb0 + q * 8;  // + rt*16*N + it*64 + kh*32

    uint4 sreg[4];
    int4 aregA[8], aregB[8];  // [rt*2+kh]*2 + {0,1}

    auto load_stage = [&](int it) {
#pragma unroll
        for (int u = 0; u < 4; u++) {
            int unit = u * 256 + t;
            int r = unit >> 3, s = unit & 7;
            sreg[u] = *reinterpret_cast<const uint4*>(vb + (size_t)r * N + it * BK + s * 8);
        }
    };
    auto write_stage = [&](int pb) {
#pragma unroll
        for (int u = 0; u < 4; u++) {
            int unit = u * 256 + t;
            int r = unit >> 3, s = unit & 7;
            *reinterpret_cast<uint4*>(&bs[pb][r][s * 8]) = sreg[u];
        }
    };
    auto load_adj = [&](int it, int4* ar) {
#pragma unroll
        for (int rt = 0; rt < 2; rt++)
#pragma unroll
            for (int kh = 0; kh < 2; kh++) {
                const int* p = adjbase + (size_t)rt * 16 * N + it * BK + kh * 32;
                ar[(rt * 2 + kh) * 2 + 0] = *reinterpret_cast<const int4*>(p);
                ar[(rt * 2 + kh) * 2 + 1] = *reinterpret_cast<const int4*>(p + 4);
            }
    };

    float4v acc0[8], acc1[8];
#pragma unroll
    for (int nt = 0; nt < 8; nt++) {
        acc0[nt] = (float4v){0.f, 0.f, 0.f, 0.f};
        acc1[nt] = (float4v){0.f, 0.f, 0.f, 0.f};
    }
    float den0 = 0.f, den1 = 0.f;

    // w-gen: 8 masked-selected weights -> bf16 A-frag
    auto gen_af = [&](const int4& a0, const int4& a1, const float4& x2a, const float4& x2b,
                      const float4& p2a, const float4& p2b, const float4& q2a, const float4& q2b,
                      float p1, float q1, float t1, float& den) -> short8 {
        float w0 = a0.x ? ((x2a.x >= t1) ? p1 * p2a.x : q1 * q2a.x) : 0.f;
        float w1 = a0.y ? ((x2a.y >= t1) ? p1 * p2a.y : q1 * q2a.y) : 0.f;
        float w2 = a0.z ? ((x2a.z >= t1) ? p1 * p2a.z : q1 * q2a.z) : 0.f;
        float w3 = a0.w ? ((x2a.w >= t1) ? p1 * p2a.w : q1 * q2a.w) : 0.f;
        float w4 = a1.x ? ((x2b.x >= t1) ? p1 * p2b.x : q1 * q2b.x) : 0.f;
        float w5 = a1.y ? ((x2b.y >= t1) ? p1 * p2b.y : q1 * q2b.y) : 0.f;
        float w6 = a1.z ? ((x2b.z >= t1) ? p1 * p2b.z : q1 * q2b.z) : 0.f;
        float w7 = a1.w ? ((x2b.w >= t1) ? p1 * p2b.w : q1 * q2b.w) : 0.f;
        den += ((w0 + w1) + (w2 + w3)) + ((w4 + w5) + (w6 + w7));
        union { short8 s; uint4 u; } r;
        r.u.x = pack_bf2(w0, w1); r.u.y = pack_bf2(w2, w3);
        r.u.z = pack_bf2(w4, w5); r.u.w = pack_bf2(w6, w7);
        return r.s;
    };

    auto body = [&](int it, int4* cur, int4* nxt, int pb) {
        if (it + 1 < NIT) {  // prefetch next iteration (latency hidden under compute)
            load_stage(it + 1);
            load_adj(it + 1, nxt);
        }
#pragma unroll
        for (int kh = 0; kh < 2; kh++) {
            int jl = it * BK + kh * 32 + q * 8;
            float4 x2a = *reinterpret_cast<const float4*>(&sW2[jl]);
            float4 x2b = *reinterpret_cast<const float4*>(&sW2[jl + 4]);
            float4 p2a = *reinterpret_cast<const float4*>(&sP2[jl]);
            float4 p2b = *reinterpret_cast<const float4*>(&sP2[jl + 4]);
            float4 q2a = *reinterpret_cast<const float4*>(&sQ2[jl]);
            float4 q2b = *reinterpret_cast<const float4*>(&sQ2[jl + 4]);
            short8 af0 = gen_af(cur[kh * 2 + 0], cur[kh * 2 + 1], x2a, x2b, p2a, p2b, q2a, q2b,
                                p1a, q1a, t1a, den0);
            short8 af1 = gen_af(cur[(2 + kh) * 2 + 0], cur[(2 + kh) * 2 + 1], x2a, x2b, p2a, p2b,
                                q2a, q2b, p1b, q1b, t1b, den1);
#pragma unroll
            for (int nt = 0; nt < 8; nt++) {
                short8 bf = *reinterpret_cast<const short8*>(&bs[pb][nt * 16 + m][kh * 32 + q * 8]);
                acc0[nt] = __builtin_amdgcn_mfma_f32_16x16x32_bf16(af0, bf, acc0[nt], 0, 0, 0);
                acc1[nt] = __builtin_amdgcn_mfma_f32_16x16x32_bf16(af1, bf, acc1[nt], 0, 0, 0);
            }
        }
        if (it + 1 < NIT) write_stage(pb ^ 1);
        __syncthreads();
    };

    // prologue
    load_stage(0);
    load_adj(0, aregA);
    write_stage(0);
    __syncthreads();

#pragma unroll 1
    for (int ith = 0; ith < NIT / 2; ith++) {
        body(ith * 2 + 0, aregA, aregB, 0);
        body(ith * 2 + 1, aregB, aregA, 1);
    }

    // epilogue: denominators (reduce over q) + partial numerators, plain stores
    den0 += __shfl_xor(den0, 16); den0 += __shfl_xor(den0, 32);
    den1 += __shfl_xor(den1, 16); den1 += __shfl_xor(den1, 32);
    float* dp = den_part + (size_t)split * BN;
    if (q == 0) { dp[gi0] = den0; dp[gi1] = den1; }
    float* hp = h_part + (size_t)split * BN * F;
    int orow0 = b * N + r0 + q * 4;  // C/D: row = q*4+reg (within 16-tile), col = m
#pragma unroll
    for (int nt = 0; nt < 8; nt++)
#pragma unroll
        for (int r = 0; r < 4; r++) {
            hp[(size_t)(orow0 + r) * F + nt * 16 + m] = acc0[nt][r];
            hp[(size_t)(orow0 + 16 + r) * F + nt * 16 + m] = acc1[nt][r];
        }
}

// ---------------- K4: out = leaky( ((sum_s h_s)/(sum_s den_s)) @ Wo^T ) ----------------
__global__ __launch_bounds__(256) void k_out(const float* __restrict__ h_part,
                                             const float* __restrict__ den_part,
                                             const float* __restrict__ Wo_w,
                                             float* __restrict__ out) {
    __shared__ float hs[32][F];    // 16 KB
    __shared__ float Ws[F][129];   // 66 KB
    int t = threadIdx.x;
    int row0 = blockIdx.x * 32;    // flat row in [0, BN)
    {
        const float4* src = reinterpret_cast<const float4*>(Wo_w);
#pragma unroll
        for (int u = 0; u < 16; u++) {
            int unit = u * 256 + t;
            int r = unit >> 5, s = unit & 31;
            float4 val = src[unit];
            Ws[r][s * 4 + 0] = val.x; Ws[r][s * 4 + 1] = val.y;
            Ws[r][s * 4 + 2] = val.z; Ws[r][s * 4 + 3] = val.w;
        }
    }
#pragma unroll
    for (int u = 0; u < 4; u++) {
        int unit = u * 256 + t;
        int r = unit >> 5, s = unit & 31;
        size_t off = (size_t)(row0 + r) * F + s * 4;
        float4 h0 = *reinterpret_cast<const float4*>(h_part + off);
        float4 h1 = *reinterpret_cast<const float4*>(h_part + (size_t)BN * F + off);
        float4 h2 = *reinterpret_cast<const float4*>(h_part + (size_t)2 * BN * F + off);
        float4 h3 = *reinterpret_cast<const float4*>(h_part + (size_t)3 * BN * F + off);
        float dsum = den_part[row0 + r] + den_part[BN + row0 + r] +
                     den_part[2 * BN + row0 + r] + den_part[3 * BN + row0 + r];
        float inv = 1.f / dsum;
        hs[r][s * 4 + 0] = (h0.x + h1.x + h2.x + h3.x) * inv;
        hs[r][s * 4 + 1] = (h0.y + h1.y + h2.y + h3.y) * inv;
        hs[r][s * 4 + 2] = (h0.z + h1.z + h2.z + h3.z) * inv;
        hs[r][s * 4 + 3] = (h0.w + h1.w + h2.w + h3.w) * inv;
    }
    __syncthreads();
    int f = t & 127, g = t >> 7;
    float acc[16];
#pragma unroll
    for (int r = 0; r < 16; r++) acc[r] = 0.f;
    for (int kk = 0; kk < F; kk++) {
        float wk = Ws[f][kk];
#pragma unroll
        for (int r = 0; r < 16; r++) acc[r] = fmaf(hs[g * 16 + r][kk], wk, acc[r]);
    }
#pragma unroll
    for (int r = 0; r < 16; r++) out[(size_t)(row0 + g * 16 + r) * F + f] = leaky(acc[r]);
}

extern "C" void kernel_launch(void* const* d_in, const int* in_sizes, int n_in,
                              void* d_out, int out_size, void* d_ws, size_t ws_size,
                              hipStream_t stream) {
    const float* q    = (const float*)d_in[0];
    const float* k    = (const float*)d_in[1];
    const float* v    = (const float*)d_in[2];
    const int*   adj  = (const int*)d_in[3];
    const float* Wq_w = (const float*)d_in[4];
    const float* Wq_b = (const float*)d_in[5];
    const float* Wk_w = (const float*)d_in[6];
    const float* Wk_b = (const float*)d_in[7];
    const float* Wv_w = (const float*)d_in[8];
    const float* Wv_b = (const float*)d_in[9];
    const float* a    = (const float*)d_in[10];
    const float* Wo_w = (const float*)d_in[11];
    float* out = (float*)d_out;
    float* ws = (float*)d_ws;

    unsigned short* vpT = (unsigned short*)ws;        // BN*F bf16 = BN*F/2 floats
    float* h_part   = ws + BN * F / 2;                // SPLITS*BN*F
    float* den_part = h_part + (size_t)SPLITS * BN * F;  // SPLITS*BN
    float* Wh1 = den_part + SPLITS * BN;
    float* Wh2 = Wh1 + BN;
    float* P1  = Wh2 + BN;
    float* Q1  = P1 + BN;
    float* P2  = Q1 + BN;
    float* Q2  = P2 + BN;
    float* c1  = Q2 + BN;                             // F
    float* c2  = c1 + F;                              // F
    float* d12 = c2 + F;                              // 2
    float* M2  = d12 + 2;                             // B

    k_prep<<<1, 256, 0, stream>>>(Wq_w, Wq_b, Wk_w, Wk_b, a, c1, c2, d12);
    k_wh<<<BN / 8, 256, 0, stream>>>(q, k, c1, c2, d12, Wh1, Wh2);
    k_max2<<<B, 256, 0, stream>>>(Wh2, M2);
    k_tab<<<BN / 256, 256, 0, stream>>>(Wh1, Wh2, M2, P1, Q1, P2, Q2);
    k_vp<<<BN / 32, 256, 0, stream>>>(v, Wv_w, Wv_b, vpT);
    k_attn<<<B * 32 * SPLITS, 256, 0, stream>>>(vpT, adj, Wh1, P1, Q1, P2, Q2, Wh2,
                                                h_part, den_part);
    k_out<<<BN / 32, 256, 0, stream>>>(h_part, den_part, Wo_w, out);
}